// Round 3
// baseline (1021.136 us; speedup 1.0000x reference)
//
#include <hip/hip_runtime.h>
#include <hip/hip_bf16.h>

// LSTMDecoder: B=4096, LATENT=128, SEQ=512, HID=32, OUT=64
// Inputs float32, output float32 (reference dtypes). Internal math fp32.
// Harness compares after bf16-rounding with 2% absmax threshold.
//
// Design:
//  - grid = 1024 blocks x 128 threads; block owns NR=4 batch rows for all 512 steps.
//  - lane (tid) -> gate g = q*32 + j  (q = tid&3 = gate type i/f/g/o, j = tid>>2 = cell idx).
//    W_hh[g][0:32] held in 32 VGPRs; h broadcast from LDS (uniform-address ds_read_b128).
//  - after activation, 4x4 butterfly transpose in lane quads redistributes (i,f,g,o)
//    so lane (j,q) updates cell state c for local row q, col j. c lives in 1 VGPR.
//  - projection fused: same lanes, out_W[lane][0:32] in 32 VGPRs; wave w does rows {2w,2w+1};
//    64 lanes store contiguous f32 (256 B coalesced) per (row,t).
//  - one __syncthreads per step; double-buffered h in LDS (rows padded to 36 floats,
//    36*4=144 B keeps rows 16 B-aligned; array force-aligned 16 for b128 reads).

#define B_SZ   4096
#define LATENT 128
#define SEQ    512
#define HID    32
#define OUT_N  64
#define NR     4
#define NTHR   128
#define HPAD   36

__device__ __forceinline__ float fexp2(float x) { return __builtin_amdgcn_exp2f(x); }
__device__ __forceinline__ float frcp(float x)  { return __builtin_amdgcn_rcpf(x); }
// tanh(x) = 1 - 2/(1 + 2^(2x*log2e));  sigmoid(x) = 1/(1 + 2^(-x*log2e))
__device__ __forceinline__ float tanh_f(float x) {
    return fmaf(-2.f, frcp(1.f + fexp2(2.88539008177792681f * x)), 1.f);
}

__global__ __launch_bounds__(NTHR)
void lstm_kernel(const float* __restrict__ z,
                 const float* __restrict__ init_W,
                 const float* __restrict__ init_b,
                 const float* __restrict__ W_hh,
                 const float* __restrict__ b_ih,
                 const float* __restrict__ b_hh,
                 const float* __restrict__ out_W,
                 const float* __restrict__ out_b,
                 float* __restrict__ y)
{
    __shared__ __align__(16) float hb[2][NR * HPAD];

    const int tid  = threadIdx.x;
    const int wave = tid >> 6;
    const int lane = tid & 63;
    const int j    = tid >> 2;      // 0..31 cell index
    const int q    = tid & 3;       // gate type: 0=i 1=f 2=g 3=o
    const int g    = q * HID + j;   // gate row in W_hh (PyTorch i,f,g,o order)
    const int rbase = blockIdx.x * NR;

    // ---- weights to registers ----
    float w[HID];
    {
        const float4* wp = (const float4*)(W_hh + (size_t)g * HID);
#pragma unroll
        for (int i = 0; i < 8; i++) {
            float4 v = wp[i];
            w[i*4+0] = v.x; w[i*4+1] = v.y; w[i*4+2] = v.z; w[i*4+3] = v.w;
        }
    }
    float ow[HID];
    {
        const float4* wp = (const float4*)(out_W + (size_t)lane * HID);
#pragma unroll
        for (int i = 0; i < 8; i++) {
            float4 v = wp[i];
            ow[i*4+0] = v.x; ow[i*4+1] = v.y; ow[i*4+2] = v.z; ow[i*4+3] = v.w;
        }
    }
    const float bias = b_ih[g] + b_hh[g];
    const float ob   = out_b[lane];
    const float actm = (q == 2) ? 2.88539008177792681f : -1.44269504088896341f;

    // ---- h0 = z @ init_W.T + init_b : this thread computes h0[local row q][j] ----
    {
        float acc = init_b[j];
        const float4* zr = (const float4*)(z + (size_t)(rbase + q) * LATENT);
        const float4* iw = (const float4*)(init_W + (size_t)j * LATENT);
#pragma unroll 8
        for (int k = 0; k < LATENT / 4; k++) {
            float4 a4 = zr[k], b4 = iw[k];
            acc = fmaf(a4.x, b4.x, acc);
            acc = fmaf(a4.y, b4.y, acc);
            acc = fmaf(a4.z, b4.z, acc);
            acc = fmaf(a4.w, b4.w, acc);
        }
        hb[0][q * HPAD + j] = acc;
    }
    float c_r = 0.f;   // cell state for (local row q, col j)
    __syncthreads();

    // projection output pointers: wave w handles rows 2w, 2w+1; element = lane
    float* yp0 = y + (size_t)(rbase + 2 * wave + 0) * SEQ * OUT_N + lane;
    float* yp1 = y + (size_t)(rbase + 2 * wave + 1) * SEQ * OUT_N + lane;

    int p = 0;
    for (int t = 0; t < SEQ; t++) {
        // ---- gates: this lane's gate g for all 4 rows ----
        float a[NR];
#pragma unroll
        for (int r = 0; r < NR; r++) {
            const float4* hp = (const float4*)&hb[p][r * HPAD];
            float4 h4[8];
#pragma unroll
            for (int i = 0; i < 8; i++) h4[i] = hp[i];
            float acc = bias;
#pragma unroll
            for (int i = 0; i < 8; i++) {
                acc = fmaf(w[i*4+0], h4[i].x, acc);
                acc = fmaf(w[i*4+1], h4[i].y, acc);
                acc = fmaf(w[i*4+2], h4[i].z, acc);
                acc = fmaf(w[i*4+3], h4[i].w, acc);
            }
            a[r] = acc;
        }
        // ---- activations (sigmoid for q!=2, tanh for q==2) ----
#pragma unroll
        for (int r = 0; r < NR; r++) {
            float s = frcp(1.f + fexp2(a[r] * actm));
            a[r] = (q == 2) ? fmaf(-2.f, s, 1.f) : s;
        }
        // ---- 4x4 butterfly transpose within lane quads:
        // before: lane q holds its gate type for rows 0..3
        // after:  lane q holds (i,f,g,o) for row q
        float sx0 = __shfl_xor(a[0], 1), sx1 = __shfl_xor(a[1], 1);
        float sx2 = __shfl_xor(a[2], 1), sx3 = __shfl_xor(a[3], 1);
        const bool q0 = (q & 1);
        float b0 = q0 ? sx1 : a[0];
        float b1 = q0 ? a[1] : sx0;
        float b2 = q0 ? sx3 : a[2];
        float b3 = q0 ? a[3] : sx2;
        float sy0 = __shfl_xor(b0, 2), sy1 = __shfl_xor(b1, 2);
        float sy2 = __shfl_xor(b2, 2), sy3 = __shfl_xor(b3, 2);
        const bool q1 = (q & 2);
        float gi = q1 ? sy2 : b0;
        float gf = q1 ? sy3 : b1;
        float gg = q1 ? b2 : sy0;
        float go = q1 ? b3 : sy1;
        // ---- c/h update for (local row q, col j) ----
        float cn = fmaf(gf, c_r, gi * gg);
        c_r = cn;
        float hn = go * tanh_f(cn);
        hb[p ^ 1][q * HPAD + j] = hn;
        __syncthreads();
        // ---- projection: y[row][t][lane] = out_W[lane] . h_new[row] + out_b ----
#pragma unroll
        for (int rr = 0; rr < 2; rr++) {
            const float4* hp = (const float4*)&hb[p ^ 1][(2 * wave + rr) * HPAD];
            float4 h4[8];
#pragma unroll
            for (int i = 0; i < 8; i++) h4[i] = hp[i];
            float acc = ob;
#pragma unroll
            for (int i = 0; i < 8; i++) {
                acc = fmaf(ow[i*4+0], h4[i].x, acc);
                acc = fmaf(ow[i*4+1], h4[i].y, acc);
                acc = fmaf(ow[i*4+2], h4[i].z, acc);
                acc = fmaf(ow[i*4+3], h4[i].w, acc);
            }
            float* yp = rr ? yp1 : yp0;
            yp[(size_t)t * OUT_N] = acc;
        }
        p ^= 1;
    }
}

extern "C" void kernel_launch(void* const* d_in, const int* in_sizes, int n_in,
                              void* d_out, int out_size, void* d_ws, size_t ws_size,
                              hipStream_t stream) {
    const float* z      = (const float*)d_in[0];
    const float* init_W = (const float*)d_in[1];
    const float* init_b = (const float*)d_in[2];
    // d_in[3] = W_ih: unused (x input is all zeros; only biases survive)
    const float* W_hh   = (const float*)d_in[4];
    const float* b_ih   = (const float*)d_in[5];
    const float* b_hh   = (const float*)d_in[6];
    const float* out_W  = (const float*)d_in[7];
    const float* out_b  = (const float*)d_in[8];
    float* yout = (float*)d_out;

    lstm_kernel<<<B_SZ / NR, NTHR, 0, stream>>>(z, init_W, init_b, W_hh, b_ih, b_hh,
                                                out_W, out_b, yout);
}

// Round 4
// 867.525 us; speedup vs baseline: 1.1771x; 1.1771x over previous
//
#include <hip/hip_runtime.h>

// LSTMDecoder: B=4096, LATENT=128, SEQ=512, HID=32, OUT=64. f32 in/out.
// Round 4: MFMA recurrence. One wave owns 16 batch rows for all 512 steps.
//  - gates[16x128] = h[16x32] @ W_hh^T       -> 8x mfma_f32_16x16x32_f16
//  - y_t[16x64]    = h[16x32] @ out_W^T      -> 4x mfma_f32_16x16x32_f16
//  - A-frag (h, f16) round-trips through LDS each step (layout transform
//    C/D->A); single-wave block => NO __syncthreads anywhere.
//  - c stays fp32 in registers; D-layout makes i,f,g,o for a (row,cell)
//    lane-local (same lane/reg, tiles n: i=0,1 f=2,3 g=4,5 o=6,7).
//  - W_hh/out_W quantized once to f16 B-fragments (resident VGPRs);
//    biases pre-baked into C-operand fragments.

#define B_SZ   4096
#define LATENT 128
#define SEQ    512
#define HID    32
#define OUT_N  64
#define ROWS   16     // rows per wave
#define LSW    40     // LDS h row stride in halves (80 B, 16B-aligned, de-conflicted)

typedef _Float16 f16x8 __attribute__((ext_vector_type(8)));
typedef float    f32x4 __attribute__((ext_vector_type(4)));

__device__ __forceinline__ float fexp2(float x) { return __builtin_amdgcn_exp2f(x); }
__device__ __forceinline__ float frcp(float x)  { return __builtin_amdgcn_rcpf(x); }
__device__ __forceinline__ float sigm(float x) {
    return frcp(1.f + fexp2(-1.44269504088896341f * x));
}
__device__ __forceinline__ float tanh_f(float x) {
    return fmaf(-2.f, frcp(1.f + fexp2(2.88539008177792681f * x)), 1.f);
}
__device__ __forceinline__ f16x8 cvt8(const float* p) {
    f16x8 r;
#pragma unroll
    for (int i = 0; i < 8; i++) r[i] = (_Float16)p[i];
    return r;
}

__global__ __launch_bounds__(64)
void lstm_mfma(const float* __restrict__ z,
               const float* __restrict__ init_W,
               const float* __restrict__ init_b,
               const float* __restrict__ W_hh,
               const float* __restrict__ b_ih,
               const float* __restrict__ b_hh,
               const float* __restrict__ out_W,
               const float* __restrict__ out_b,
               float* __restrict__ y)
{
    __shared__ __align__(16) _Float16 hst[ROWS * LSW];

    const int lane = threadIdx.x;          // 0..63, single wave
    const int n_   = lane & 15;            // tile column (and C/D col)
    const int kb   = lane >> 4;            // k-group for A/B; row-group for C/D
    const int rbase = blockIdx.x * ROWS;

    // ---- resident B-fragments + bias C-fragments ----
    // B-layout (mirrors verified A-layout): lane(kb,n_) holds B[k=kb*8+i][n_].
    // gates tile n: B[k][n'] = W_hh[n*16+n'][k]   (g-rows contiguous in k)
    f16x8 bhh[8], bow[4];
    f32x4 bacc[8], oacc[4];
#pragma unroll
    for (int n = 0; n < 8; n++) {
        int g = n * 16 + n_;
        bhh[n] = cvt8(W_hh + (size_t)g * HID + kb * 8);
        float b = b_ih[g] + b_hh[g];
        bacc[n] = (f32x4){b, b, b, b};
    }
#pragma unroll
    for (int n = 0; n < 4; n++) {
        int col = n * 16 + n_;
        bow[n] = cvt8(out_W + (size_t)col * HID + kb * 8);
        float b = out_b[col];
        oacc[n] = (f32x4){b, b, b, b};
    }

    // ---- h0 = z @ init_W^T + init_b (fp32 VALU, one-time) ----
    // lane covers cells idx = ii*64 + lane  ->  (m = ii*2 + lane/32, j = lane&31)
#pragma unroll
    for (int ii = 0; ii < 8; ii++) {
        int m = ii * 2 + (lane >> 5);
        int j = lane & 31;
        const float4* zp = (const float4*)(z + (size_t)(rbase + m) * LATENT);
        const float4* wp = (const float4*)(init_W + (size_t)j * LATENT);
        float acc = init_b[j];
#pragma unroll
        for (int k = 0; k < LATENT / 4; k++) {
            float4 a4 = zp[k], b4 = wp[k];
            acc = fmaf(a4.x, b4.x, acc); acc = fmaf(a4.y, b4.y, acc);
            acc = fmaf(a4.z, b4.z, acc); acc = fmaf(a4.w, b4.w, acc);
        }
        hst[m * LSW + j] = (_Float16)acc;
    }

    float c8[8];   // c[jj*4+r] for (row kb*4+r, cell n_+16*jj), fp32
#pragma unroll
    for (int i = 0; i < 8; i++) c8[i] = 0.f;

    // output base: row (rbase + kb*4), col n_, t=0
    float* yt = y + (size_t)(rbase + kb * 4) * SEQ * OUT_N + n_;

    // A-fragment of h: lane(kb, m=n_) holds h[m][kb*8 .. kb*8+7]
    f16x8 a = *(const f16x8*)&hst[n_ * LSW + kb * 8];

    for (int t = 0; t < SEQ; t++) {
        // ---- gates: D[n][r] = preact(row kb*4+r, gate n*16+n_) ----
        f32x4 acc[8];
#pragma unroll
        for (int n = 0; n < 8; n++)
            acc[n] = __builtin_amdgcn_mfma_f32_16x16x32_f16(a, bhh[n], bacc[n], 0, 0, 0);

        // ---- activations + state update (lane-local) ----
#pragma unroll
        for (int jj = 0; jj < 2; jj++) {
#pragma unroll
            for (int r = 0; r < 4; r++) {
                float gi = sigm(acc[0 + jj][r]);
                float gf = sigm(acc[2 + jj][r]);
                float gg = tanh_f(acc[4 + jj][r]);
                float go = sigm(acc[6 + jj][r]);
                float cn = fmaf(gf, c8[jj * 4 + r], gi * gg);
                c8[jj * 4 + r] = cn;
                float hn = go * tanh_f(cn);
                hst[(kb * 4 + r) * LSW + jj * 16 + n_] = (_Float16)hn;
            }
        }

        // ---- reload A-frag (h_t); wave-coherent LDS, no barrier needed ----
        a = *(const f16x8*)&hst[n_ * LSW + kb * 8];

        // ---- projection: y_t[16x64] = h_t @ out_W^T + out_b ----
        f32x4 py[4];
#pragma unroll
        for (int n = 0; n < 4; n++)
            py[n] = __builtin_amdgcn_mfma_f32_16x16x32_f16(a, bow[n], oacc[n], 0, 0, 0);

#pragma unroll
        for (int n = 0; n < 4; n++) {
#pragma unroll
            for (int r = 0; r < 4; r++)
                yt[(size_t)r * SEQ * OUT_N + n * 16] = py[n][r];
        }
        yt += OUT_N;
    }
}

extern "C" void kernel_launch(void* const* d_in, const int* in_sizes, int n_in,
                              void* d_out, int out_size, void* d_ws, size_t ws_size,
                              hipStream_t stream) {
    const float* z      = (const float*)d_in[0];
    const float* init_W = (const float*)d_in[1];
    const float* init_b = (const float*)d_in[2];
    // d_in[3] = W_ih: unused (x input is all zeros; only biases survive)
    const float* W_hh   = (const float*)d_in[4];
    const float* b_ih   = (const float*)d_in[5];
    const float* b_hh   = (const float*)d_in[6];
    const float* out_W  = (const float*)d_in[7];
    const float* out_b  = (const float*)d_in[8];
    float* yout = (float*)d_out;

    lstm_mfma<<<B_SZ / ROWS, 64, 0, stream>>>(z, init_W, init_b, W_hh, b_ih, b_hh,
                                              out_W, out_b, yout);
}

// Round 5
// 691.748 us; speedup vs baseline: 1.4762x; 1.2541x over previous
//
#include <hip/hip_runtime.h>

// LSTMDecoder: B=4096, LATENT=128, SEQ=512, HID=32, OUT=64. f32 in/out.
// Round 5: 4 waves/block (one per SIMD), 16 batch rows per block, grid=256.
//  - Gate MFMAs duplicated per wave-pair (MFMA is ~2% utilized - duplication free):
//    waves {0,1} compute gate tiles {jj=0}: i,f,g,o cells 0-15; waves {2,3}: cells 16-31.
//  - Activation work split by D-frag REG index: wave parity p2 takes regs {2p2,2p2+1}
//    (rows = 0,1 vs 2,3 mod 4). No cross-lane exchange; all 64 lanes active;
//    20 transcendentals/lane/step instead of 80, spread over 4 SIMDs.
//  - Projection: 4 tiles, one per wave.
//  - Double-buffered h in LDS + raw `s_waitcnt lgkmcnt(0); s_barrier` (no vmcnt
//    drain -> y stores stay in flight across the barrier). One barrier/step.
//  - c state fp32 in regs (2/lane); h carried as f16 (verified: absmax = bf16 quantum).

#define B_SZ   4096
#define LATENT 128
#define SEQ    512
#define HID    32
#define OUT_N  64
#define ROWS   16
#define LSW    40    // h row stride in halves (80 B; 16B-aligned rows)

typedef _Float16 f16x8 __attribute__((ext_vector_type(8)));
typedef float    f32x4 __attribute__((ext_vector_type(4)));

__device__ __forceinline__ float fexp2(float x) { return __builtin_amdgcn_exp2f(x); }
__device__ __forceinline__ float frcp(float x)  { return __builtin_amdgcn_rcpf(x); }
__device__ __forceinline__ float sigm(float x) {
    return frcp(1.f + fexp2(-1.44269504088896341f * x));
}
__device__ __forceinline__ float tanh_f(float x) {
    return fmaf(-2.f, frcp(1.f + fexp2(2.88539008177792681f * x)), 1.f);
}
__device__ __forceinline__ f16x8 cvt8(const float* p) {
    f16x8 r;
#pragma unroll
    for (int i = 0; i < 8; i++) r[i] = (_Float16)p[i];
    return r;
}
// Workgroup barrier WITHOUT the compiler's vmcnt(0) drain: LDS ops only.
__device__ __forceinline__ void lds_barrier() {
    asm volatile("s_waitcnt lgkmcnt(0)\n\ts_barrier" ::: "memory");
}

__global__ __launch_bounds__(256)
void lstm_mfma4(const float* __restrict__ z,
                const float* __restrict__ init_W,
                const float* __restrict__ init_b,
                const float* __restrict__ W_hh,
                const float* __restrict__ b_ih,
                const float* __restrict__ b_hh,
                const float* __restrict__ out_W,
                const float* __restrict__ out_b,
                float* __restrict__ y)
{
    __shared__ __align__(16) _Float16 hst[2][ROWS * LSW];

    const int tid  = threadIdx.x;
    const int w    = tid >> 6;          // wave 0..3
    const int lane = tid & 63;
    const int n_   = lane & 15;         // tile col
    const int kb   = lane >> 4;         // k-group / row-group
    const int jj   = w >> 1;            // cell half: 0 -> cells 0-15, 1 -> 16-31
    const int p2   = w & 1;             // reg pair: regs {2p2, 2p2+1}
    const int rbase = blockIdx.x * ROWS;

    // ---- resident B-frags (per wave: its 4 gate tiles + 1 proj tile) ----
    f16x8 bhh[4], bow;
    f32x4 bacc[4], oacc;
#pragma unroll
    for (int m = 0; m < 4; m++) {
        int g = (2 * m + jj) * 16 + n_;          // tiles jj, 2+jj, 4+jj, 6+jj
        bhh[m] = cvt8(W_hh + (size_t)g * HID + kb * 8);
        float b = b_ih[g] + b_hh[g];
        bacc[m] = (f32x4){b, b, b, b};
    }
    {
        int col = w * 16 + n_;
        bow = cvt8(out_W + (size_t)col * HID + kb * 8);
        float b = out_b[col];
        oacc = (f32x4){b, b, b, b};
    }

    // ---- h0 = z @ init_W^T + init_b (one-time, 2 elements/thread) ----
#pragma unroll
    for (int i = 0; i < 2; i++) {
        int e = tid + 256 * i;           // 0..511
        int m = e >> 5, j = e & 31;
        const float4* zp = (const float4*)(z + (size_t)(rbase + m) * LATENT);
        const float4* wp = (const float4*)(init_W + (size_t)j * LATENT);
        float acc = init_b[j];
#pragma unroll
        for (int k = 0; k < LATENT / 4; k++) {
            float4 a4 = zp[k], b4 = wp[k];
            acc = fmaf(a4.x, b4.x, acc); acc = fmaf(a4.y, b4.y, acc);
            acc = fmaf(a4.z, b4.z, acc); acc = fmaf(a4.w, b4.w, acc);
        }
        hst[0][m * LSW + j] = (_Float16)acc;
    }
    __syncthreads();

    float c2[2] = {0.f, 0.f};  // c for (row kb*4 + 2p2 + r2, cell jj*16 + n_)

    // A-fragment: lane(kb, m=n_) holds h[m][kb*8 .. +7]
    f16x8 a = *(const f16x8*)&hst[0][n_ * LSW + kb * 8];

    float* yb = y + (size_t)(rbase + kb * 4) * SEQ * OUT_N + w * 16 + n_;

    int p = 0;
    for (int t = 0; t < SEQ; t++) {
        // ---- gates for this wave's 4 tiles (duplicated across wave pair) ----
        f32x4 acc[4];
#pragma unroll
        for (int m = 0; m < 4; m++)
            acc[m] = __builtin_amdgcn_mfma_f32_16x16x32_f16(a, bhh[m], bacc[m], 0, 0, 0);

        // ---- activations + state update: this wave's 2 regs ----
#pragma unroll
        for (int r2 = 0; r2 < 2; r2++) {
            int r = 2 * p2 + r2;
            float gi = sigm(acc[0][r]);
            float gf = sigm(acc[1][r]);
            float gg = tanh_f(acc[2][r]);
            float go = sigm(acc[3][r]);
            float cn = fmaf(gf, c2[r2], gi * gg);
            c2[r2] = cn;
            float hn = go * tanh_f(cn);
            hst[p ^ 1][(kb * 4 + r) * LSW + jj * 16 + n_] = (_Float16)hn;
        }

        lds_barrier();

        // ---- reload A-frag = h_{t+1}; project this wave's tile; store ----
        a = *(const f16x8*)&hst[p ^ 1][n_ * LSW + kb * 8];
        f32x4 py = __builtin_amdgcn_mfma_f32_16x16x32_f16(a, bow, oacc, 0, 0, 0);
#pragma unroll
        for (int r = 0; r < 4; r++)
            yb[(size_t)r * SEQ * OUT_N + (size_t)t * OUT_N] = py[r];

        p ^= 1;
    }
}

extern "C" void kernel_launch(void* const* d_in, const int* in_sizes, int n_in,
                              void* d_out, int out_size, void* d_ws, size_t ws_size,
                              hipStream_t stream) {
    const float* z      = (const float*)d_in[0];
    const float* init_W = (const float*)d_in[1];
    const float* init_b = (const float*)d_in[2];
    // d_in[3] = W_ih: unused (x input is all zeros; only biases survive)
    const float* W_hh   = (const float*)d_in[4];
    const float* b_ih   = (const float*)d_in[5];
    const float* b_hh   = (const float*)d_in[6];
    const float* out_W  = (const float*)d_in[7];
    const float* out_b  = (const float*)d_in[8];
    float* yout = (float*)d_out;

    lstm_mfma4<<<B_SZ / ROWS, 256, 0, stream>>>(z, init_W, init_b, W_hh, b_ih, b_hh,
                                                out_W, out_b, yout);
}